// Round 1
// baseline (271.643 us; speedup 1.0000x reference)
//
#include <hip/hip_runtime.h>

// ---------------------------------------------------------------------------
// DiscriminatorMBD: conv1->relu->pool -> conv2->relu->pool -> feats[512,640]
//   M = feats @ T^T  [512,1024] ; dist_ij_b = sum_c |M[i,b,c]-M[j,b,c]|
//   closeness[i,b] = sum_j exp(-dist) ; head = sigmoid(fc2(relu(fc1(concat))))
// All fp32.
// ---------------------------------------------------------------------------

#define NB 512

// ---- kernel 1: conv1 (1->20ch, 5x5 VALID on 28x28) + relu + 2x2 maxpool ----
// one block per image, 256 threads. out: [512][20][12][12]
__global__ __launch_bounds__(256) void k1_conv1_pool(
    const float* __restrict__ x, const float* __restrict__ w,
    const float* __restrict__ bias, float* __restrict__ out) {
  __shared__ float img[784];   // 28*28
  __shared__ float wl[500];    // 20*25
  __shared__ float bl[20];
  const int imgId = blockIdx.x;
  const float* xi = x + imgId * 784;
  for (int t = threadIdx.x; t < 784; t += 256) img[t] = xi[t];
  for (int t = threadIdx.x; t < 500; t += 256) wl[t] = w[t];
  if (threadIdx.x < 20) bl[threadIdx.x] = bias[threadIdx.x];
  __syncthreads();
  // 20ch * 12 * 12 = 2880 pooled outputs
  for (int o = threadIdx.x; o < 2880; o += 256) {
    const int ch = o / 144;
    const int rem = o - ch * 144;
    const int py = rem / 12;
    const int px = rem - py * 12;
    const float* wc = &wl[ch * 25];
    const int oy = py * 2, ox = px * 2;
    float s00 = 0.f, s01 = 0.f, s10 = 0.f, s11 = 0.f;
#pragma unroll
    for (int ky = 0; ky < 5; ++ky) {
#pragma unroll
      for (int kx = 0; kx < 5; ++kx) {
        const float ww = wc[ky * 5 + kx];
        const float* ip = &img[(oy + ky) * 28 + ox + kx];
        s00 += ip[0] * ww;
        s01 += ip[1] * ww;
        s10 += ip[28] * ww;
        s11 += ip[29] * ww;
      }
    }
    const float m = fmaxf(fmaxf(s00, s01), fmaxf(s10, s11)) + bl[ch];
    out[imgId * 2880 + o] = fmaxf(m, 0.f);
  }
}

// ---- kernel 2: conv2 (20->40ch, 5x5 on 12x12) + relu + 2x2 pool -> feats ----
// one block per image, 128 threads: thread = (chg 0..7, pos 0..15),
// owns 5 channels x 4 conv positions (20 accumulators). Weights staged per-ic.
__global__ __launch_bounds__(128) void k2_conv2_pool(
    const float* __restrict__ h1, const float* __restrict__ w,
    const float* __restrict__ bias, float* __restrict__ feats) {
  __shared__ float in[2880];   // 20*12*12
  __shared__ float wl[1000];   // 40ch * 25 (one input channel slice)
  const int imgId = blockIdx.x;
  for (int t = threadIdx.x; t < 2880; t += 128) in[t] = h1[imgId * 2880 + t];
  const int pos = threadIdx.x & 15;  // 0..15  (py,px)
  const int chg = threadIdx.x >> 4;  // 0..7   (5 channels each)
  const int py = pos >> 2, px = pos & 3;
  const int oy = py * 2, ox = px * 2;
  float acc[5][4];
#pragma unroll
  for (int q = 0; q < 5; ++q)
#pragma unroll
    for (int p = 0; p < 4; ++p) acc[q][p] = 0.f;

  for (int ic = 0; ic < 20; ++ic) {
    __syncthreads();  // previous wl readers done (and iter0: `in` staged)
    for (int t = threadIdx.x; t < 1000; t += 128) {
      const int ch = t / 25, k = t - ch * 25;
      wl[t] = w[ch * 500 + ic * 25 + k];
    }
    __syncthreads();
    const float* ib = &in[ic * 144 + oy * 12 + ox];
    const float* wb = &wl[chg * 5 * 25];
#pragma unroll
    for (int ky = 0; ky < 5; ++ky) {
#pragma unroll
      for (int kx = 0; kx < 5; ++kx) {
        const float i00 = ib[ky * 12 + kx];
        const float i01 = ib[ky * 12 + kx + 1];
        const float i10 = ib[ky * 12 + kx + 12];
        const float i11 = ib[ky * 12 + kx + 13];
#pragma unroll
        for (int q = 0; q < 5; ++q) {
          const float ww = wb[q * 25 + ky * 5 + kx];
          acc[q][0] += i00 * ww;
          acc[q][1] += i01 * ww;
          acc[q][2] += i10 * ww;
          acc[q][3] += i11 * ww;
        }
      }
    }
  }
#pragma unroll
  for (int q = 0; q < 5; ++q) {
    const int ch = chg * 5 + q;
    const float m =
        fmaxf(fmaxf(acc[q][0], acc[q][1]), fmaxf(acc[q][2], acc[q][3])) +
        bias[ch];
    feats[imgId * 640 + ch * 16 + pos] = fmaxf(m, 0.f);
  }
}

// ---- kernel 3: M = feats[512,640] @ T^T  (T is [1024,640]) -> M[512,1024] ----
// 64(i) x 32(j) tile, 256 threads, 4x2 microtile, K-tiles of 16.
__global__ __launch_bounds__(256) void k3_gemm(
    const float* __restrict__ A, const float* __restrict__ Bm,
    float* __restrict__ C) {
  __shared__ float As[16][65];
  __shared__ float Bs[16][33];
  const int tid = threadIdx.x;
  const int tx = tid & 15;   // j micro
  const int ty = tid >> 4;   // i micro
  const int i0 = blockIdx.y * 64;
  const int j0 = blockIdx.x * 32;
  float acc[4][2];
#pragma unroll
  for (int u = 0; u < 4; ++u)
#pragma unroll
    for (int v = 0; v < 2; ++v) acc[u][v] = 0.f;

  for (int k0 = 0; k0 < 640; k0 += 16) {
    {  // load A tile 64x16 (float4 per thread)
      const int m = tid >> 2, kq = tid & 3;
      const float4 av =
          *reinterpret_cast<const float4*>(A + (i0 + m) * 640 + k0 + kq * 4);
      As[kq * 4 + 0][m] = av.x;
      As[kq * 4 + 1][m] = av.y;
      As[kq * 4 + 2][m] = av.z;
      As[kq * 4 + 3][m] = av.w;
    }
    if (tid < 128) {  // load B tile 32x16
      const int n = tid >> 2, kq = tid & 3;
      const float4 bv =
          *reinterpret_cast<const float4*>(Bm + (j0 + n) * 640 + k0 + kq * 4);
      Bs[kq * 4 + 0][n] = bv.x;
      Bs[kq * 4 + 1][n] = bv.y;
      Bs[kq * 4 + 2][n] = bv.z;
      Bs[kq * 4 + 3][n] = bv.w;
    }
    __syncthreads();
#pragma unroll
    for (int kk = 0; kk < 16; ++kk) {
      float a0 = As[kk][ty * 4 + 0];
      float a1 = As[kk][ty * 4 + 1];
      float a2 = As[kk][ty * 4 + 2];
      float a3 = As[kk][ty * 4 + 3];
      float b0 = Bs[kk][tx * 2 + 0];
      float b1 = Bs[kk][tx * 2 + 1];
      acc[0][0] += a0 * b0; acc[0][1] += a0 * b1;
      acc[1][0] += a1 * b0; acc[1][1] += a1 * b1;
      acc[2][0] += a2 * b0; acc[2][1] += a2 * b1;
      acc[3][0] += a3 * b0; acc[3][1] += a3 * b1;
    }
    __syncthreads();
  }
#pragma unroll
  for (int u = 0; u < 4; ++u)
#pragma unroll
    for (int v = 0; v < 2; ++v)
      C[(i0 + ty * 4 + u) * 1024 + j0 + tx * 2 + v] = acc[u][v];
}

// ---- kernel 4: closeness[i,b] = sum_j exp(-sum_c |M[i,b,c]-M[j,b,c]|) ----
// one block per i, 256 threads: b = t&63, wave g = t>>6 handles 128 j's.
__global__ __launch_bounds__(256) void k4_mbd(const float* __restrict__ M,
                                              float* __restrict__ close) {
  const int i = blockIdx.x;
  const int t = threadIdx.x;
  const int b = t & 63;
  const int g = t >> 6;
  const float4* mip = reinterpret_cast<const float4*>(M + i * 1024 + b * 16);
  const float4 mi0 = mip[0], mi1 = mip[1], mi2 = mip[2], mi3 = mip[3];
  float acc = 0.f;
  for (int jj = 0; jj < 128; ++jj) {
    const int j = g * 128 + jj;
    const float4* mjp = reinterpret_cast<const float4*>(M + j * 1024 + b * 16);
    const float4 a = mjp[0], bb = mjp[1], c = mjp[2], d = mjp[3];
    float dist = fabsf(mi0.x - a.x) + fabsf(mi0.y - a.y) + fabsf(mi0.z - a.z) +
                 fabsf(mi0.w - a.w);
    dist += fabsf(mi1.x - bb.x) + fabsf(mi1.y - bb.y) + fabsf(mi1.z - bb.z) +
            fabsf(mi1.w - bb.w);
    dist += fabsf(mi2.x - c.x) + fabsf(mi2.y - c.y) + fabsf(mi2.z - c.z) +
            fabsf(mi2.w - c.w);
    dist += fabsf(mi3.x - d.x) + fabsf(mi3.y - d.y) + fabsf(mi3.z - d.z) +
            fabsf(mi3.w - d.w);
    acc += __expf(-dist);
  }
  __shared__ float red[4][64];
  red[g][b] = acc;
  __syncthreads();
  if (t < 64) {
    close[i * 64 + t] = red[0][t] + red[1][t] + red[2][t] + red[3][t];
  }
}

// ---- kernel 5: out = sigmoid(fc2(relu(fc1(concat(feats, closeness))))) ----
// one block per image, 128 threads (100 active for fc1 rows).
__global__ __launch_bounds__(128) void k5_head(
    const float* __restrict__ feats, const float* __restrict__ close,
    const float* __restrict__ w1, const float* __restrict__ b1,
    const float* __restrict__ w2, const float* __restrict__ b2,
    float* __restrict__ out) {
  __shared__ float v[704];
  __shared__ float h[100];
  const int i = blockIdx.x;
  for (int t = threadIdx.x; t < 640; t += 128) v[t] = feats[i * 640 + t];
  if (threadIdx.x < 64) v[640 + threadIdx.x] = close[i * 64 + threadIdx.x];
  __syncthreads();
  const int k = threadIdx.x;
  if (k < 100) {
    const float* wr = w1 + k * 704;
    float s = b1[k];
#pragma unroll 4
    for (int d = 0; d < 704; d += 4) {
      const float4 wv = *reinterpret_cast<const float4*>(wr + d);
      s += v[d] * wv.x + v[d + 1] * wv.y + v[d + 2] * wv.z + v[d + 3] * wv.w;
    }
    h[k] = fmaxf(s, 0.f) * w2[k];
  }
  __syncthreads();
  if (threadIdx.x == 0) {
    float s = b2[0];
#pragma unroll 4
    for (int q = 0; q < 100; ++q) s += h[q];
    out[i] = 1.f / (1.f + __expf(-s));
  }
}

extern "C" void kernel_launch(void* const* d_in, const int* in_sizes, int n_in,
                              void* d_out, int out_size, void* d_ws,
                              size_t ws_size, hipStream_t stream) {
  const float* x   = (const float*)d_in[0];
  const float* c1w = (const float*)d_in[1];
  const float* c1b = (const float*)d_in[2];
  const float* c2w = (const float*)d_in[3];
  const float* c2b = (const float*)d_in[4];
  const float* T   = (const float*)d_in[5];
  const float* f1w = (const float*)d_in[6];
  const float* f1b = (const float*)d_in[7];
  const float* f2w = (const float*)d_in[8];
  const float* f2b = (const float*)d_in[9];
  float* out = (float*)d_out;

  float* h1    = (float*)d_ws;             // 512*2880 = 1474560 f
  float* feats = h1 + 512 * 2880;          // 512*640  =  327680 f
  float* M     = feats + 512 * 640;        // 512*1024 =  524288 f
  float* close = M + 512 * 1024;           // 512*64   =   32768 f
  // total ws use: 2359296 floats = 9.44 MB

  k1_conv1_pool<<<NB, 256, 0, stream>>>(x, c1w, c1b, h1);
  k2_conv2_pool<<<NB, 128, 0, stream>>>(h1, c2w, c2b, feats);
  k3_gemm<<<dim3(32, 8), 256, 0, stream>>>(feats, T, M);
  k4_mbd<<<NB, 256, 0, stream>>>(M, close);
  k5_head<<<NB, 128, 0, stream>>>(feats, close, f1w, f1b, f2w, f2b, out);
}

// Round 2
// 203.797 us; speedup vs baseline: 1.3329x; 1.3329x over previous
//
#include <hip/hip_runtime.h>

// ---------------------------------------------------------------------------
// DiscriminatorMBD pipeline, all fp32:
//  k1: conv1(1->20,5x5)+relu+pool -> h1[512][20][12][12]
//  k2: conv2(20->40,5x5)+relu+pool -> feats[512][640]  (layout [ch][pos16])
//  k3: M = feats @ T^T -> M[512][1024]
//  k4: partial closeness over j-quarters -> cp[16][512][64]
//  k5: concat + fc1 + relu + fc2 + sigmoid -> out[512]
// ---------------------------------------------------------------------------

#define NB 512

// ---- kernel 1: conv1 + relu + 2x2 maxpool ---------------------------------
// one block per image, 256 threads. Register-blocked 6x6 patch per output.
__global__ __launch_bounds__(256) void k1_conv1_pool(
    const float* __restrict__ x, const float* __restrict__ w,
    const float* __restrict__ bias, float* __restrict__ out) {
  __shared__ float img[784];   // 28*28
  __shared__ float wl[500];    // 20*25
  __shared__ float bl[20];
  const int imgId = blockIdx.x;
  {
    const float4* src = reinterpret_cast<const float4*>(x + imgId * 784);
    float4* dst = reinterpret_cast<float4*>(img);
    for (int t = threadIdx.x; t < 196; t += 256) dst[t] = src[t];
  }
  for (int t = threadIdx.x; t < 500; t += 256) wl[t] = w[t];
  if (threadIdx.x < 20) bl[threadIdx.x] = bias[threadIdx.x];
  __syncthreads();

  for (int o = threadIdx.x; o < 2880; o += 256) {
    const int ch = o / 144;
    const int rem = o - ch * 144;
    const int py = rem / 12;
    const int px = rem - py * 12;
    const int oy = py * 2, ox = px * 2;
    // load 6x6 patch into registers via float2 LDS reads
    float p[6][6];
    const float* ib = &img[oy * 28 + ox];
#pragma unroll
    for (int r = 0; r < 6; ++r) {
      const float2 v0 = *reinterpret_cast<const float2*>(&ib[r * 28 + 0]);
      const float2 v1 = *reinterpret_cast<const float2*>(&ib[r * 28 + 2]);
      const float2 v2 = *reinterpret_cast<const float2*>(&ib[r * 28 + 4]);
      p[r][0] = v0.x; p[r][1] = v0.y; p[r][2] = v1.x;
      p[r][3] = v1.y; p[r][4] = v2.x; p[r][5] = v2.y;
    }
    const float* wc = &wl[ch * 25];
    float s00 = 0.f, s01 = 0.f, s10 = 0.f, s11 = 0.f;
#pragma unroll
    for (int ky = 0; ky < 5; ++ky) {
#pragma unroll
      for (int kx = 0; kx < 5; ++kx) {
        const float ww = wc[ky * 5 + kx];
        s00 += p[ky][kx] * ww;
        s01 += p[ky][kx + 1] * ww;
        s10 += p[ky + 1][kx] * ww;
        s11 += p[ky + 1][kx + 1] * ww;
      }
    }
    const float m = fmaxf(fmaxf(s00, s01), fmaxf(s10, s11)) + bl[ch];
    out[imgId * 2880 + o] = fmaxf(m, 0.f);
  }
}

// ---- kernel 2: conv2 + relu + pool ----------------------------------------
// one block per image, 256 threads = (half h, chg 0..7, pos 0..15).
// half h sums input channels h*10..h*10+9; partials merged via LDS.
// Weights LDS layout: wt[half][parity][tap][oc-slot(64)], slot = chg*8+q.
__global__ __launch_bounds__(256) void k2_conv2_pool(
    const float* __restrict__ h1, const float* __restrict__ w,
    const float* __restrict__ bias, float* __restrict__ feats) {
  __shared__ float in[2880];
  __shared__ float wt[2][2][25][64];
  __shared__ float part[128][21];
  const int imgId = blockIdx.x;
  const int tid = threadIdx.x;
  const int h = tid >> 7;            // 0..1
  const int chg = (tid >> 4) & 7;    // 0..7
  const int pos = tid & 15;          // 0..15
  const int py = pos >> 2, px = pos & 3;
  const int oy = py * 2, ox = px * 2;

  {  // stage input image (float4)
    const float4* src = reinterpret_cast<const float4*>(h1 + imgId * 2880);
    float4* dst = reinterpret_cast<float4*>(in);
    for (int t = tid; t < 720; t += 256) dst[t] = src[t];
  }
  // stage first weight chunk: ic=0 (half0) and ic=10 (half1) into parity 0
  for (int e = tid; e < 2000; e += 256) {
    const int eh = (e >= 1000) ? 1 : 0;
    const int e2 = e - eh * 1000;
    const int oc = e2 / 25, tap = e2 - oc * 25;
    wt[eh][0][tap][(oc / 5) * 8 + (oc - (oc / 5) * 5)] =
        w[oc * 500 + (eh ? 10 : 0) * 25 + tap];
  }
  __syncthreads();

  float acc[5][4];
#pragma unroll
  for (int q = 0; q < 5; ++q)
#pragma unroll
    for (int pp = 0; pp < 4; ++pp) acc[q][pp] = 0.f;

  for (int s = 0; s < 10; ++s) {
    const int p0 = s & 1;
    // T14 split: issue next chunk's global loads early
    float sv[8];
    if (s < 9) {
#pragma unroll
      for (int k = 0; k < 8; ++k) {
        const int e = tid + k * 256;
        if (e < 2000) {
          const int eh = (e >= 1000) ? 1 : 0;
          const int e2 = e - eh * 1000;
          const int oc = e2 / 25, tap = e2 - oc * 25;
          const int ic = eh ? (11 + s) : (s + 1);
          sv[k] = w[oc * 500 + ic * 25 + tap];
        }
      }
    }
    // compute my ic from parity p0
    const int myic = h * 10 + s;
    float p[6][6];
    {
      const float* ib = &in[myic * 144 + oy * 12 + ox];
#pragma unroll
      for (int r = 0; r < 6; ++r) {
        const float2 v0 = *reinterpret_cast<const float2*>(&ib[r * 12 + 0]);
        const float2 v1 = *reinterpret_cast<const float2*>(&ib[r * 12 + 2]);
        const float2 v2 = *reinterpret_cast<const float2*>(&ib[r * 12 + 4]);
        p[r][0] = v0.x; p[r][1] = v0.y; p[r][2] = v1.x;
        p[r][3] = v1.y; p[r][4] = v2.x; p[r][5] = v2.y;
      }
    }
#pragma unroll
    for (int ky = 0; ky < 5; ++ky) {
#pragma unroll
      for (int kx = 0; kx < 5; ++kx) {
        const int tap = ky * 5 + kx;
        const float4 w4 =
            *reinterpret_cast<const float4*>(&wt[h][p0][tap][chg * 8]);
        const float w4b = wt[h][p0][tap][chg * 8 + 4];
        const float i00 = p[ky][kx];
        const float i01 = p[ky][kx + 1];
        const float i10 = p[ky + 1][kx];
        const float i11 = p[ky + 1][kx + 1];
        acc[0][0] += i00 * w4.x; acc[0][1] += i01 * w4.x;
        acc[0][2] += i10 * w4.x; acc[0][3] += i11 * w4.x;
        acc[1][0] += i00 * w4.y; acc[1][1] += i01 * w4.y;
        acc[1][2] += i10 * w4.y; acc[1][3] += i11 * w4.y;
        acc[2][0] += i00 * w4.z; acc[2][1] += i01 * w4.z;
        acc[2][2] += i10 * w4.z; acc[2][3] += i11 * w4.z;
        acc[3][0] += i00 * w4.w; acc[3][1] += i01 * w4.w;
        acc[3][2] += i10 * w4.w; acc[3][3] += i11 * w4.w;
        acc[4][0] += i00 * w4b; acc[4][1] += i01 * w4b;
        acc[4][2] += i10 * w4b; acc[4][3] += i11 * w4b;
      }
    }
    // write staged weights late, one barrier per chunk
    if (s < 9) {
#pragma unroll
      for (int k = 0; k < 8; ++k) {
        const int e = tid + k * 256;
        if (e < 2000) {
          const int eh = (e >= 1000) ? 1 : 0;
          const int e2 = e - eh * 1000;
          const int oc = e2 / 25, tap = e2 - oc * 25;
          wt[eh][(s + 1) & 1][tap][(oc / 5) * 8 + (oc - (oc / 5) * 5)] = sv[k];
        }
      }
    }
    __syncthreads();
  }

  // merge halves: upper writes partials, lower finalizes
  if (tid >= 128) {
    const int t2 = tid - 128;
#pragma unroll
    for (int q = 0; q < 5; ++q)
#pragma unroll
      for (int pp = 0; pp < 4; ++pp) part[t2][q * 4 + pp] = acc[q][pp];
  }
  __syncthreads();
  if (tid < 128) {
#pragma unroll
    for (int q = 0; q < 5; ++q) {
      const int ch = chg * 5 + q;
      const float a0 = acc[q][0] + part[tid][q * 4 + 0];
      const float a1 = acc[q][1] + part[tid][q * 4 + 1];
      const float a2 = acc[q][2] + part[tid][q * 4 + 2];
      const float a3 = acc[q][3] + part[tid][q * 4 + 3];
      const float m = fmaxf(fmaxf(a0, a1), fmaxf(a2, a3)) + bias[ch];
      feats[imgId * 640 + ch * 16 + pos] = fmaxf(m, 0.f);
    }
  }
}

// ---- kernel 3: M = feats[512,640] @ T^T (T[1024,640]) -> M[512,1024] ------
// 64(i) x 32(j) tile, 256 threads, 4x2 micro, vectorized LDS fragments.
__global__ __launch_bounds__(256) void k3_gemm(
    const float* __restrict__ A, const float* __restrict__ Bm,
    float* __restrict__ C) {
  __shared__ float As[16][68];  // stride 68 floats = 272 B (16B aligned rows)
  __shared__ float Bs[16][36];  // stride 36 floats = 144 B (8B aligned rows)
  const int tid = threadIdx.x;
  const int tx = tid & 15;
  const int ty = tid >> 4;
  const int i0 = blockIdx.y * 64;
  const int j0 = blockIdx.x * 32;
  float acc[4][2];
#pragma unroll
  for (int u = 0; u < 4; ++u)
#pragma unroll
    for (int v = 0; v < 2; ++v) acc[u][v] = 0.f;

  for (int k0 = 0; k0 < 640; k0 += 16) {
    {
      const int m = tid >> 2, kq = tid & 3;
      const float4 av =
          *reinterpret_cast<const float4*>(A + (i0 + m) * 640 + k0 + kq * 4);
      As[kq * 4 + 0][m] = av.x;
      As[kq * 4 + 1][m] = av.y;
      As[kq * 4 + 2][m] = av.z;
      As[kq * 4 + 3][m] = av.w;
    }
    if (tid < 128) {
      const int n = tid >> 2, kq = tid & 3;
      const float4 bv =
          *reinterpret_cast<const float4*>(Bm + (j0 + n) * 640 + k0 + kq * 4);
      Bs[kq * 4 + 0][n] = bv.x;
      Bs[kq * 4 + 1][n] = bv.y;
      Bs[kq * 4 + 2][n] = bv.z;
      Bs[kq * 4 + 3][n] = bv.w;
    }
    __syncthreads();
#pragma unroll
    for (int kk = 0; kk < 16; ++kk) {
      const float4 a4 = *reinterpret_cast<const float4*>(&As[kk][ty * 4]);
      const float2 b2 = *reinterpret_cast<const float2*>(&Bs[kk][tx * 2]);
      acc[0][0] += a4.x * b2.x; acc[0][1] += a4.x * b2.y;
      acc[1][0] += a4.y * b2.x; acc[1][1] += a4.y * b2.y;
      acc[2][0] += a4.z * b2.x; acc[2][1] += a4.z * b2.y;
      acc[3][0] += a4.w * b2.x; acc[3][1] += a4.w * b2.y;
    }
    __syncthreads();
  }
#pragma unroll
  for (int u = 0; u < 4; ++u) {
    float2 st = make_float2(acc[u][0], acc[u][1]);
    *reinterpret_cast<float2*>(&C[(i0 + ty * 4 + u) * 1024 + j0 + tx * 2]) = st;
  }
}

// ---- kernel 4: partial closeness over j-quarters --------------------------
// 512 blocks = (ig 0..31) x (jq 0..15); 256 threads = (g 0..3, b 0..63).
// thread keeps mi for 4 i's in registers; block covers 16 i x 32 j.
__global__ __launch_bounds__(256) void k4_mbd(const float* __restrict__ M,
                                              float* __restrict__ cp) {
  const int bid = blockIdx.x;
  const int ig = bid >> 4;
  const int jq = bid & 15;
  const int t = threadIdx.x;
  const int b = t & 63;
  const int g = t >> 6;
  const int i0 = ig * 16 + g * 4;
  float4 mi[4][4];
#pragma unroll
  for (int u = 0; u < 4; ++u) {
    const float4* mp = reinterpret_cast<const float4*>(M + (i0 + u) * 1024 + b * 16);
    mi[u][0] = mp[0]; mi[u][1] = mp[1]; mi[u][2] = mp[2]; mi[u][3] = mp[3];
  }
  float acc[4] = {0.f, 0.f, 0.f, 0.f};
  for (int jj = 0; jj < 32; ++jj) {
    const int j = jq * 32 + jj;
    const float4* mjp = reinterpret_cast<const float4*>(M + j * 1024 + b * 16);
    const float4 mj0 = mjp[0], mj1 = mjp[1], mj2 = mjp[2], mj3 = mjp[3];
#pragma unroll
    for (int u = 0; u < 4; ++u) {
      float dist =
          fabsf(mi[u][0].x - mj0.x) + fabsf(mi[u][0].y - mj0.y) +
          fabsf(mi[u][0].z - mj0.z) + fabsf(mi[u][0].w - mj0.w) +
          fabsf(mi[u][1].x - mj1.x) + fabsf(mi[u][1].y - mj1.y) +
          fabsf(mi[u][1].z - mj1.z) + fabsf(mi[u][1].w - mj1.w) +
          fabsf(mi[u][2].x - mj2.x) + fabsf(mi[u][2].y - mj2.y) +
          fabsf(mi[u][2].z - mj2.z) + fabsf(mi[u][2].w - mj2.w) +
          fabsf(mi[u][3].x - mj3.x) + fabsf(mi[u][3].y - mj3.y) +
          fabsf(mi[u][3].z - mj3.z) + fabsf(mi[u][3].w - mj3.w);
      acc[u] += __expf(-dist);
    }
  }
#pragma unroll
  for (int u = 0; u < 4; ++u)
    cp[(jq * 512 + i0 + u) * 64 + b] = acc[u];
}

// ---- kernel 5: head -------------------------------------------------------
__global__ __launch_bounds__(128) void k5_head(
    const float* __restrict__ feats, const float* __restrict__ cp,
    const float* __restrict__ w1, const float* __restrict__ b1,
    const float* __restrict__ w2, const float* __restrict__ b2,
    float* __restrict__ out) {
  __shared__ float v[704];
  __shared__ float hb[100];
  const int i = blockIdx.x;
  for (int t = threadIdx.x; t < 640; t += 128) v[t] = feats[i * 640 + t];
  if (threadIdx.x < 64) {
    float s = 0.f;
#pragma unroll
    for (int q = 0; q < 16; ++q) s += cp[(q * 512 + i) * 64 + threadIdx.x];
    v[640 + threadIdx.x] = s;
  }
  __syncthreads();
  const int k = threadIdx.x;
  if (k < 100) {
    const float* wr = w1 + k * 704;
    float s = b1[k];
#pragma unroll 4
    for (int d = 0; d < 704; d += 4) {
      const float4 wv = *reinterpret_cast<const float4*>(wr + d);
      s += v[d] * wv.x + v[d + 1] * wv.y + v[d + 2] * wv.z + v[d + 3] * wv.w;
    }
    hb[k] = fmaxf(s, 0.f) * w2[k];
  }
  __syncthreads();
  if (threadIdx.x == 0) {
    float s = b2[0];
#pragma unroll 4
    for (int q = 0; q < 100; ++q) s += hb[q];
    out[i] = 1.f / (1.f + __expf(-s));
  }
}

extern "C" void kernel_launch(void* const* d_in, const int* in_sizes, int n_in,
                              void* d_out, int out_size, void* d_ws,
                              size_t ws_size, hipStream_t stream) {
  const float* x   = (const float*)d_in[0];
  const float* c1w = (const float*)d_in[1];
  const float* c1b = (const float*)d_in[2];
  const float* c2w = (const float*)d_in[3];
  const float* c2b = (const float*)d_in[4];
  const float* T   = (const float*)d_in[5];
  const float* f1w = (const float*)d_in[6];
  const float* f1b = (const float*)d_in[7];
  const float* f2w = (const float*)d_in[8];
  const float* f2b = (const float*)d_in[9];
  float* out = (float*)d_out;

  float* h1    = (float*)d_ws;             // 512*2880 = 1474560 f (reused as cp)
  float* feats = h1 + 512 * 2880;          // 512*640
  float* M     = feats + 512 * 640;        // 512*1024
  float* cp    = h1;                        // 16*512*64 = 524288 f, overlays h1
  // ws use: 2326528 floats = 9.3 MB

  k1_conv1_pool<<<NB, 256, 0, stream>>>(x, c1w, c1b, h1);
  k2_conv2_pool<<<NB, 256, 0, stream>>>(h1, c2w, c2b, feats);
  k3_gemm<<<dim3(32, 8), 256, 0, stream>>>(feats, T, M);
  k4_mbd<<<NB, 256, 0, stream>>>(M, cp);
  k5_head<<<NB, 128, 0, stream>>>(feats, cp, f1w, f1b, f2w, f2b, out);
}

// Round 4
// 195.445 us; speedup vs baseline: 1.3899x; 1.0427x over previous
//
#include <hip/hip_runtime.h>

// ---------------------------------------------------------------------------
// DiscriminatorMBD pipeline, all fp32:
//  k0: reorder conv2 weights -> wstage[ocHalf][ic20][tap25][slot32]
//  k1: conv1(1->20,5x5)+relu+pool  (2 blocks/img: ch-halves) -> h1[512][20][144]
//  k2: conv2(20->40,5x5)+relu+pool (2 blocks/img: oc-halves) -> feats[512][640]
//  k3: M = feats @ T^T -> M[512][1024]   (16x32 tiles, 1024 blocks)
//  k4: partial closeness, LDS-staged swizzled j-rows -> cp[16][512][64]
//  k5: concat + fc1 + relu + fc2 + sigmoid (wave-per-row, shuffle reduce)
// ---------------------------------------------------------------------------

// ---- kernel 0: weight transform for conv2 ---------------------------------
// dst e = ((ocHalf*20 + ic)*25 + tap)*32 + grp*8 + q  ; oc = ocHalf*20+grp*5+q
__global__ __launch_bounds__(256) void k0_wxform(const float* __restrict__ w,
                                                 float* __restrict__ ws) {
  const int e = blockIdx.x * 256 + threadIdx.x;
  if (e >= 32000) return;
  const int ocHalf = e / 16000;
  const int r = e - ocHalf * 16000;
  const int ic = r / 800;
  const int r2 = r - ic * 800;
  const int tap = r2 >> 5;
  const int slot = r2 & 31;
  const int q = slot & 7;
  const int grp = slot >> 3;
  float val = 0.f;
  if (q < 5) val = w[(ocHalf * 20 + grp * 5 + q) * 500 + ic * 25 + tap];
  ws[e] = val;
}

// ---- kernel 1: conv1 + relu + 2x2 maxpool ---------------------------------
// grid 1024 = (img, chHalf). 128 threads.
__global__ __launch_bounds__(128) void k1_conv1_pool(
    const float* __restrict__ x, const float* __restrict__ w,
    const float* __restrict__ bias, float* __restrict__ out) {
  __shared__ __align__(16) float img[784];
  __shared__ float wl[250];
  __shared__ float bl[10];
  const int imgId = blockIdx.x >> 1;
  const int half = blockIdx.x & 1;
  {
    const float4* src = reinterpret_cast<const float4*>(x + imgId * 784);
    float4* dst = reinterpret_cast<float4*>(img);
    for (int t = threadIdx.x; t < 196; t += 128) dst[t] = src[t];
  }
  for (int t = threadIdx.x; t < 250; t += 128) wl[t] = w[half * 250 + t];
  if (threadIdx.x < 10) bl[threadIdx.x] = bias[half * 10 + threadIdx.x];
  __syncthreads();

  for (int o = threadIdx.x; o < 1440; o += 128) {
    const int chl = o / 144;
    const int rem = o - chl * 144;
    const int py = rem / 12;
    const int px = rem - py * 12;
    const int oy = py * 2, ox = px * 2;
    float p[6][6];
    const float* ib = &img[oy * 28 + ox];
#pragma unroll
    for (int r = 0; r < 6; ++r) {
      const float2 v0 = *reinterpret_cast<const float2*>(&ib[r * 28 + 0]);
      const float2 v1 = *reinterpret_cast<const float2*>(&ib[r * 28 + 2]);
      const float2 v2 = *reinterpret_cast<const float2*>(&ib[r * 28 + 4]);
      p[r][0] = v0.x; p[r][1] = v0.y; p[r][2] = v1.x;
      p[r][3] = v1.y; p[r][4] = v2.x; p[r][5] = v2.y;
    }
    const float* wc = &wl[chl * 25];
    float s00 = 0.f, s01 = 0.f, s10 = 0.f, s11 = 0.f;
#pragma unroll
    for (int ky = 0; ky < 5; ++ky) {
#pragma unroll
      for (int kx = 0; kx < 5; ++kx) {
        const float ww = wc[ky * 5 + kx];
        s00 += p[ky][kx] * ww;
        s01 += p[ky][kx + 1] * ww;
        s10 += p[ky + 1][kx] * ww;
        s11 += p[ky + 1][kx + 1] * ww;
      }
    }
    const float m = fmaxf(fmaxf(s00, s01), fmaxf(s10, s11)) + bl[chl];
    out[imgId * 2880 + half * 1440 + o] = fmaxf(m, 0.f);
  }
}

// ---- kernel 2: conv2 + relu + pool ----------------------------------------
// grid 1024 = (img, ocHalf). 128 threads = (h: ic-half, grp 0..3, pos 0..15).
// Weights from pre-transformed wstage; staging is identity copy (no conflicts).
__global__ __launch_bounds__(128) void k2_conv2_pool(
    const float* __restrict__ h1, const float* __restrict__ wsx,
    const float* __restrict__ bias, float* __restrict__ feats) {
  __shared__ __align__(16) float in[2880];
  __shared__ __align__(16) float wl[2][2][25][32];  // [h][parity][tap][slot]
  __shared__ float part[64][21];
  const int imgId = blockIdx.x >> 1;
  const int half = blockIdx.x & 1;
  const int tid = threadIdx.x;
  const int h = tid >> 6;
  const int grp = (tid >> 4) & 3;
  const int pos = tid & 15;
  const int py = pos >> 2, px = pos & 3;
  const int oy = py * 2, ox = px * 2;

  {
    const float4* src = reinterpret_cast<const float4*>(h1 + imgId * 2880);
    float4* dst = reinterpret_cast<float4*>(in);
    for (int t = tid; t < 720; t += 128) dst[t] = src[t];
  }
  const float4* wsrc = reinterpret_cast<const float4*>(wsx) + half * 4000;
  float4* wdst = reinterpret_cast<float4*>(wl);
  {  // initial stage: s=0 (thread-h halves ic={0,10}), parity 0
#pragma unroll
    for (int k = 0; k < 4; ++k) {
      const int e = tid + k * 128;
      if (e < 400) {
        const int hs = (e >= 200) ? 1 : 0;
        const int idx = e - hs * 200;
        wdst[hs * 400 + idx] = wsrc[(hs * 10 + 0) * 200 + idx];
      }
    }
  }
  __syncthreads();

  float acc[5][4];
#pragma unroll
  for (int q = 0; q < 5; ++q)
#pragma unroll
    for (int pp = 0; pp < 4; ++pp) acc[q][pp] = 0.f;

  for (int s = 0; s < 10; ++s) {
    const int p0 = s & 1;
    float4 sv[4];
    if (s < 9) {  // early global loads for next stage
#pragma unroll
      for (int k = 0; k < 4; ++k) {
        const int e = tid + k * 128;
        if (e < 400) {
          const int hs = (e >= 200) ? 1 : 0;
          const int idx = e - hs * 200;
          sv[k] = wsrc[(hs * 10 + s + 1) * 200 + idx];
        }
      }
    }
    const int myic = h * 10 + s;
    float p[6][6];
    {
      const float* ib = &in[myic * 144 + oy * 12 + ox];
#pragma unroll
      for (int r = 0; r < 6; ++r) {
        const float2 v0 = *reinterpret_cast<const float2*>(&ib[r * 12 + 0]);
        const float2 v1 = *reinterpret_cast<const float2*>(&ib[r * 12 + 2]);
        const float2 v2 = *reinterpret_cast<const float2*>(&ib[r * 12 + 4]);
        p[r][0] = v0.x; p[r][1] = v0.y; p[r][2] = v1.x;
        p[r][3] = v1.y; p[r][4] = v2.x; p[r][5] = v2.y;
      }
    }
#pragma unroll
    for (int ky = 0; ky < 5; ++ky) {
#pragma unroll
      for (int kx = 0; kx < 5; ++kx) {
        const int tap = ky * 5 + kx;
        const float4 w4 =
            *reinterpret_cast<const float4*>(&wl[h][p0][tap][grp * 8]);
        const float w4b = wl[h][p0][tap][grp * 8 + 4];
        const float i00 = p[ky][kx];
        const float i01 = p[ky][kx + 1];
        const float i10 = p[ky + 1][kx];
        const float i11 = p[ky + 1][kx + 1];
        acc[0][0] += i00 * w4.x; acc[0][1] += i01 * w4.x;
        acc[0][2] += i10 * w4.x; acc[0][3] += i11 * w4.x;
        acc[1][0] += i00 * w4.y; acc[1][1] += i01 * w4.y;
        acc[1][2] += i10 * w4.y; acc[1][3] += i11 * w4.y;
        acc[2][0] += i00 * w4.z; acc[2][1] += i01 * w4.z;
        acc[2][2] += i10 * w4.z; acc[2][3] += i11 * w4.z;
        acc[3][0] += i00 * w4.w; acc[3][1] += i01 * w4.w;
        acc[3][2] += i10 * w4.w; acc[3][3] += i11 * w4.w;
        acc[4][0] += i00 * w4b; acc[4][1] += i01 * w4b;
        acc[4][2] += i10 * w4b; acc[4][3] += i11 * w4b;
      }
    }
    if (s < 9) {  // late LDS writes into other parity
#pragma unroll
      for (int k = 0; k < 4; ++k) {
        const int e = tid + k * 128;
        if (e < 400) {
          const int hs = (e >= 200) ? 1 : 0;
          const int idx = e - hs * 200;
          wdst[hs * 400 + ((s + 1) & 1) * 200 + idx] = sv[k];
        }
      }
    }
    __syncthreads();
  }

  if (tid >= 64) {
    const int t2 = tid - 64;
#pragma unroll
    for (int q = 0; q < 5; ++q)
#pragma unroll
      for (int pp = 0; pp < 4; ++pp) part[t2][q * 4 + pp] = acc[q][pp];
  }
  __syncthreads();
  if (tid < 64) {
#pragma unroll
    for (int q = 0; q < 5; ++q) {
      const int ch = half * 20 + grp * 5 + q;
      const float a0 = acc[q][0] + part[tid][q * 4 + 0];
      const float a1 = acc[q][1] + part[tid][q * 4 + 1];
      const float a2 = acc[q][2] + part[tid][q * 4 + 2];
      const float a3 = acc[q][3] + part[tid][q * 4 + 3];
      const float m = fmaxf(fmaxf(a0, a1), fmaxf(a2, a3)) + bias[ch];
      feats[imgId * 640 + ch * 16 + pos] = fmaxf(m, 0.f);
    }
  }
}

// ---- kernel 3: M = feats[512,640] @ T^T (T[1024,640]) -> M[512,1024] ------
// 16(i) x 32(j) tiles, 128 threads, 2x2 micro. grid (32 j, 32 i) = 1024.
__global__ __launch_bounds__(128) void k3_gemm(
    const float* __restrict__ A, const float* __restrict__ Bm,
    float* __restrict__ C) {
  __shared__ __align__(16) float As[16][36];
  __shared__ __align__(16) float Bs[16][36];
  const int tid = threadIdx.x;
  const int tx = tid & 15;   // j micro
  const int ty = tid >> 4;   // i micro (0..7)
  const int i0 = blockIdx.y * 16;
  const int j0 = blockIdx.x * 32;
  float acc[2][2] = {{0.f, 0.f}, {0.f, 0.f}};

  for (int k0 = 0; k0 < 640; k0 += 16) {
    if (tid < 64) {  // A tile 16x16
      const int m = tid >> 2, kq = tid & 3;
      const float4 av =
          *reinterpret_cast<const float4*>(A + (i0 + m) * 640 + k0 + kq * 4);
      As[kq * 4 + 0][m] = av.x;
      As[kq * 4 + 1][m] = av.y;
      As[kq * 4 + 2][m] = av.z;
      As[kq * 4 + 3][m] = av.w;
    }
    {  // B tile 32x16
      const int n = tid >> 2, kq = tid & 3;
      const float4 bv =
          *reinterpret_cast<const float4*>(Bm + (j0 + n) * 640 + k0 + kq * 4);
      Bs[kq * 4 + 0][n] = bv.x;
      Bs[kq * 4 + 1][n] = bv.y;
      Bs[kq * 4 + 2][n] = bv.z;
      Bs[kq * 4 + 3][n] = bv.w;
    }
    __syncthreads();
#pragma unroll
    for (int kk = 0; kk < 16; ++kk) {
      const float2 a2 = *reinterpret_cast<const float2*>(&As[kk][ty * 2]);
      const float2 b2 = *reinterpret_cast<const float2*>(&Bs[kk][tx * 2]);
      acc[0][0] += a2.x * b2.x; acc[0][1] += a2.x * b2.y;
      acc[1][0] += a2.y * b2.x; acc[1][1] += a2.y * b2.y;
    }
    __syncthreads();
  }
#pragma unroll
  for (int u = 0; u < 2; ++u) {
    float2 st = make_float2(acc[u][0], acc[u][1]);
    *reinterpret_cast<float2*>(&C[(i0 + ty * 2 + u) * 1024 + j0 + tx * 2]) = st;
  }
}

// ---- kernel 4: partial closeness, LDS-staged swizzled j-rows --------------
// grid 512 = (ig 0..31, jq 0..15); 256 thr = (g 0..3, b 0..63).
// Block: 16 i (4/thread in regs) x 32 j (8 chunks of 4 rows, double-buffered).
__global__ __launch_bounds__(256) void k4_mbd(const float* __restrict__ M,
                                              float* __restrict__ cp) {
  __shared__ float4 jb4[2][4][256];  // [buf][row][swizzled f4]
  const int bid = blockIdx.x;
  const int ig = bid >> 4;
  const int jq = bid & 15;
  const int t = threadIdx.x;
  const int b = t & 63;
  const int g = t >> 6;
  const int i0 = ig * 16 + g * 4;
  const float4* Mf4 = reinterpret_cast<const float4*>(M);

  float4 mi[4][4];
#pragma unroll
  for (int u = 0; u < 4; ++u) {
#pragma unroll
    for (int q = 0; q < 4; ++q) mi[u][q] = Mf4[(i0 + u) * 256 + b * 4 + q];
  }
  // swizzled write slot for stager thread t
  const int wslot = (t >> 2) * 4 + ((t & 3) ^ ((t >> 3) & 3));
  {  // stage chunk 0
#pragma unroll
    for (int k = 0; k < 4; ++k)
      jb4[0][k][wslot] = Mf4[(jq * 32 + k) * 256 + t];
  }
  __syncthreads();

  float acc[4] = {0.f, 0.f, 0.f, 0.f};
  const int xr = (b >> 1) & 3;
  for (int c = 0; c < 8; ++c) {
    float4 st[4];
    if (c < 7) {
#pragma unroll
      for (int k = 0; k < 4; ++k)
        st[k] = Mf4[(jq * 32 + (c + 1) * 4 + k) * 256 + t];
    }
    const int cbuf = c & 1;
#pragma unroll
    for (int jj = 0; jj < 4; ++jj) {
      const float4* row = jb4[cbuf][jj];
      float4 mj[4];
#pragma unroll
      for (int q = 0; q < 4; ++q) mj[q] = row[b * 4 + (q ^ xr)];
#pragma unroll
      for (int u = 0; u < 4; ++u) {
        float dist =
            fabsf(mi[u][0].x - mj[0].x) + fabsf(mi[u][0].y - mj[0].y) +
            fabsf(mi[u][0].z - mj[0].z) + fabsf(mi[u][0].w - mj[0].w) +
            fabsf(mi[u][1].x - mj[1].x) + fabsf(mi[u][1].y - mj[1].y) +
            fabsf(mi[u][1].z - mj[1].z) + fabsf(mi[u][1].w - mj[1].w) +
            fabsf(mi[u][2].x - mj[2].x) + fabsf(mi[u][2].y - mj[2].y) +
            fabsf(mi[u][2].z - mj[2].z) + fabsf(mi[u][2].w - mj[2].w) +
            fabsf(mi[u][3].x - mj[3].x) + fabsf(mi[u][3].y - mj[3].y) +
            fabsf(mi[u][3].z - mj[3].z) + fabsf(mi[u][3].w - mj[3].w);
        acc[u] += __expf(-dist);
      }
    }
    if (c < 7) {
#pragma unroll
      for (int k = 0; k < 4; ++k) jb4[(c + 1) & 1][k][wslot] = st[k];
    }
    __syncthreads();
  }
#pragma unroll
  for (int u = 0; u < 4; ++u)
    cp[(jq * 512 + i0 + u) * 64 + b] = acc[u];
}

// ---- kernel 5: head, wave-per-row shuffle reduce --------------------------
// 512 blocks, 256 thr = 4 waves; wave w does fc1 rows w, w+4, ...
__global__ __launch_bounds__(256) void k5_head(
    const float* __restrict__ feats, const float* __restrict__ cp,
    const float* __restrict__ w1, const float* __restrict__ b1,
    const float* __restrict__ w2, const float* __restrict__ b2,
    float* __restrict__ out) {
  __shared__ __align__(16) float v[704];
  __shared__ float hb[100];
  const int i = blockIdx.x;
  const int tid = threadIdx.x;
  float4* v4 = reinterpret_cast<float4*>(v);
  if (tid < 160)
    v4[tid] = reinterpret_cast<const float4*>(feats + i * 640)[tid];
  if (tid >= 192) {
    const int bb = tid - 192;
    float s = 0.f;
#pragma unroll
    for (int q = 0; q < 16; ++q) s += cp[(q * 512 + i) * 64 + bb];
    v[640 + bb] = s;
  }
  __syncthreads();
  const int wave = tid >> 6;
  const int lane = tid & 63;
  for (int r = wave; r < 100; r += 4) {
    const float4* wr = reinterpret_cast<const float4*>(w1 + r * 704);
    const float4 wa = wr[lane];
    const float4 wb = wr[lane + 64];
    const float4 va = v4[lane];
    const float4 vb = v4[lane + 64];
    float s = wa.x * va.x + wa.y * va.y + wa.z * va.z + wa.w * va.w +
              wb.x * vb.x + wb.y * vb.y + wb.z * vb.z + wb.w * vb.w;
    if (lane < 48) {
      const float4 wc = wr[lane + 128];
      const float4 vc = v4[lane + 128];
      s += wc.x * vc.x + wc.y * vc.y + wc.z * vc.z + wc.w * vc.w;
    }
#pragma unroll
    for (int off = 32; off; off >>= 1) s += __shfl_xor(s, off);
    if (lane == 0) hb[r] = fmaxf(s + b1[r], 0.f) * w2[r];
  }
  __syncthreads();
  if (tid < 64) {
    float s = hb[tid] + ((tid < 36) ? hb[tid + 64] : 0.f);
#pragma unroll
    for (int off = 32; off; off >>= 1) s += __shfl_xor(s, off);
    if (tid == 0) out[i] = 1.f / (1.f + __expf(-(s + b2[0])));
  }
}

extern "C" void kernel_launch(void* const* d_in, const int* in_sizes, int n_in,
                              void* d_out, int out_size, void* d_ws,
                              size_t ws_size, hipStream_t stream) {
  const float* x   = (const float*)d_in[0];
  const float* c1w = (const float*)d_in[1];
  const float* c1b = (const float*)d_in[2];
  const float* c2w = (const float*)d_in[3];
  const float* c2b = (const float*)d_in[4];
  const float* T   = (const float*)d_in[5];
  const float* f1w = (const float*)d_in[6];
  const float* f1b = (const float*)d_in[7];
  const float* f2w = (const float*)d_in[8];
  const float* f2b = (const float*)d_in[9];
  float* out = (float*)d_out;

  float* h1     = (float*)d_ws;            // 512*2880 floats
  float* feats  = h1 + 512 * 2880;         // 512*640
  float* M      = feats + 512 * 640;       // 512*1024
  float* wstage = M;                       // 32000 floats, dead before k3
  float* cp     = h1;                      // 16*512*64, overlays h1 (after k2)
  // ws use: 2326528 floats = 9.3 MB (same as previous round)

  k0_wxform<<<125, 256, 0, stream>>>(c2w, wstage);
  k1_conv1_pool<<<1024, 128, 0, stream>>>(x, c1w, c1b, h1);
  k2_conv2_pool<<<1024, 128, 0, stream>>>(h1, wstage, c2b, feats);
  k3_gemm<<<dim3(32, 32), 128, 0, stream>>>(feats, T, M);
  k4_mbd<<<512, 256, 0, stream>>>(M, cp);
  k5_head<<<512, 256, 0, stream>>>(feats, cp, f1w, f1b, f2w, f2b, out);
}

// Round 5
// 175.794 us; speedup vs baseline: 1.5452x; 1.1118x over previous
//
#include <hip/hip_runtime.h>

// ---------------------------------------------------------------------------
// DiscriminatorMBD, fp32 end-to-end except GEMM (bf16x3 MFMA, ~1e-6 rel err):
//  kP: prep — conv2 weight transform ws2[ic][tap][slot64]; T -> bf16 hi/lo
//  kC: fused conv1+relu+pool + conv2+relu+pool (2 images/block, 256 blocks)
//      -> feats f32 [512][640] and bf16 hi/lo copies
//  k3m: M = feats @ T^T via mfma_f32_16x16x32_bf16 (x3 split) -> M[512][1024]
//  k4: partial closeness over j-quarters -> cp[16][512][64]
//  k5: concat + fc1 + relu + fc2 + sigmoid -> out[512]
// ---------------------------------------------------------------------------

typedef __attribute__((ext_vector_type(8))) short bf16x8;
typedef __attribute__((ext_vector_type(4))) float f32x4;

static __device__ __forceinline__ unsigned short f2bf(float x) {
  unsigned int u = __float_as_uint(x);
  unsigned int r = (u + 0x7fffu + ((u >> 16) & 1u)) >> 16;
  return (unsigned short)r;
}
static __device__ __forceinline__ float bf2f(unsigned short h) {
  return __uint_as_float(((unsigned int)h) << 16);
}

// ---- kP: weight transform + T bf16 split ----------------------------------
// ws2 flat: ((ic*25 + tap)*64 + grp*8 + q), oc = grp*5+q (q<5 valid, else 0)
__global__ __launch_bounds__(256) void kP_prep(
    const float* __restrict__ c2w, const float* __restrict__ T,
    float* __restrict__ ws2, unsigned short* __restrict__ Th,
    unsigned short* __restrict__ Tl) {
  const int idx = blockIdx.x * 256 + threadIdx.x;
  if (idx < 655360) {
    const float v = T[idx];
    const unsigned short h = f2bf(v);
    Th[idx] = h;
    Tl[idx] = f2bf(v - bf2f(h));
  }
  if (idx < 32000) {
    const int ic = idx / 1600;
    const int r = idx - ic * 1600;
    const int tap = r >> 6;
    const int slot = r & 63;
    const int grp = slot >> 3;
    const int q = slot & 7;
    float val = 0.f;
    if (q < 5) val = c2w[(grp * 5 + q) * 500 + ic * 25 + tap];
    ws2[idx] = val;
  }
}

// ---- kC: fused conv1+pool -> conv2+pool ------------------------------------
// 256 blocks x 256 thr. Block handles 2 images (slot = tid>>7).
// Per image: 128 thr. conv1: quads of 4 pooled outputs. conv2: thread =
// (h=ic-half, grp 0..7 of 5 oc, pp 0..7 pooled-pair), 1000 FMA per ic.
__global__ __launch_bounds__(256) void kC_conv(
    const float* __restrict__ x, const float* __restrict__ c1w,
    const float* __restrict__ c1b, const float* __restrict__ ws2,
    const float* __restrict__ c2b, float* __restrict__ feats,
    unsigned short* __restrict__ fh, unsigned short* __restrict__ fl) {
  __shared__ __align__(16) float img[2][784];
  __shared__ __align__(16) float h1s[2][2880];
  __shared__ float wl1[500];
  __shared__ float bl1[20];
  __shared__ float bl2[40];
  __shared__ __align__(16) float wl2[2][2][1600];  // [ic-stream][parity][tap*64+slot]
  __shared__ float mg[2][64][41];

  const int tid = threadIdx.x;
  const int slot = tid >> 7;
  const int lt = tid & 127;
  const int imgId = blockIdx.x * 2 + slot;

  {  // stage both images (float4) + conv1 weights + biases
    float4* dst = reinterpret_cast<float4*>(&img[0][0]);
    for (int t = tid; t < 392; t += 256) {
      const int which = t / 196;
      const int within = t - which * 196;
      dst[t] = reinterpret_cast<const float4*>(
          x + (blockIdx.x * 2 + which) * 784)[within];
    }
  }
  for (int t = tid; t < 500; t += 256) wl1[t] = c1w[t];
  if (tid < 20) bl1[tid] = c1b[tid];
  if (tid >= 64 && tid < 104) bl2[tid - 64] = c2b[tid - 64];
  __syncthreads();

  // ---- conv1: 720 quads per image over 128 threads ----
  for (int qd = lt; qd < 720; qd += 128) {
    const int ch = qd / 36;
    const int rem = qd - ch * 36;
    const int py = rem / 3;
    const int qx = rem - py * 3;
    const int r0 = py * 2;
    const int c0 = qx * 8;
    float p[6][12];
#pragma unroll
    for (int r = 0; r < 6; ++r) {
      const float* ib = &img[slot][(r0 + r) * 28 + c0];
      const float4 a = *reinterpret_cast<const float4*>(ib);
      const float4 b = *reinterpret_cast<const float4*>(ib + 4);
      const float4 c = *reinterpret_cast<const float4*>(ib + 8);
      p[r][0] = a.x; p[r][1] = a.y; p[r][2] = a.z; p[r][3] = a.w;
      p[r][4] = b.x; p[r][5] = b.y; p[r][6] = b.z; p[r][7] = b.w;
      p[r][8] = c.x; p[r][9] = c.y; p[r][10] = c.z; p[r][11] = c.w;
    }
    float s[16];
#pragma unroll
    for (int u = 0; u < 16; ++u) s[u] = 0.f;
    const float* wc = &wl1[ch * 25];
#pragma unroll
    for (int ky = 0; ky < 5; ++ky) {
#pragma unroll
      for (int kx = 0; kx < 5; ++kx) {
        const float w = wc[ky * 5 + kx];
#pragma unroll
        for (int u = 0; u < 4; ++u) {
#pragma unroll
          for (int dy = 0; dy < 2; ++dy) {
#pragma unroll
            for (int dx = 0; dx < 2; ++dx) {
              s[u * 4 + dy * 2 + dx] += p[ky + dy][2 * u + dx + kx] * w;
            }
          }
        }
      }
    }
    const float bb = bl1[ch];
    float4 o;
    o.x = fmaxf(fmaxf(fmaxf(s[0], s[1]), fmaxf(s[2], s[3])) + bb, 0.f);
    o.y = fmaxf(fmaxf(fmaxf(s[4], s[5]), fmaxf(s[6], s[7])) + bb, 0.f);
    o.z = fmaxf(fmaxf(fmaxf(s[8], s[9]), fmaxf(s[10], s[11])) + bb, 0.f);
    o.w = fmaxf(fmaxf(fmaxf(s[12], s[13]), fmaxf(s[14], s[15])) + bb, 0.f);
    *reinterpret_cast<float4*>(&h1s[slot][ch * 144 + py * 12 + qx * 4]) = o;
  }

  // ---- initial conv2 weight stage (parity 0): ic = 0 and ic = 10 ----
  {
    float4* wlf4 = reinterpret_cast<float4*>(&wl2[0][0][0]);
    const float4* wsf4 = reinterpret_cast<const float4*>(ws2);
#pragma unroll
    for (int k = 0; k < 4; ++k) {
      const int e = tid + k * 256;
      if (e < 800) {
        const int str = e / 400;  // ic-stream (0: ic=0.., 1: ic=10..)
        const int i4 = e - str * 400;
        wlf4[(str * 2 + 0) * 400 + i4] = wsf4[(str * 10 + 0) * 400 + i4];
      }
    }
  }
  __syncthreads();

  // ---- conv2: 10 stages, double-buffered weights ----
  const int h = lt >> 6;          // ic-half
  const int grp = (lt >> 3) & 7;  // 5-oc group
  const int pp = lt & 7;          // pooled pair
  const int oy = (pp >> 1) * 2;
  const int ox = (pp & 1) * 4;
  float acc[5][8];
#pragma unroll
  for (int q = 0; q < 5; ++q)
#pragma unroll
    for (int u = 0; u < 8; ++u) acc[q][u] = 0.f;

  float4* wlf4 = reinterpret_cast<float4*>(&wl2[0][0][0]);
  const float4* wsf4 = reinterpret_cast<const float4*>(ws2);
  for (int s = 0; s < 10; ++s) {
    const int p0 = s & 1;
    float4 sv[4];
    if (s < 9) {  // early global loads for next stage
#pragma unroll
      for (int k = 0; k < 4; ++k) {
        const int e = tid + k * 256;
        if (e < 800) {
          const int str = e / 400;
          const int i4 = e - str * 400;
          sv[k] = wsf4[(str * 10 + s + 1) * 400 + i4];
        }
      }
    }
    const int ic = h * 10 + s;
    float p[6][8];
#pragma unroll
    for (int r = 0; r < 6; ++r) {
      const float* ib = &h1s[slot][ic * 144 + (oy + r) * 12 + ox];
      const float4 a = *reinterpret_cast<const float4*>(ib);
      const float4 b = *reinterpret_cast<const float4*>(ib + 4);
      p[r][0] = a.x; p[r][1] = a.y; p[r][2] = a.z; p[r][3] = a.w;
      p[r][4] = b.x; p[r][5] = b.y; p[r][6] = b.z; p[r][7] = b.w;
    }
    const float* wbase = &wl2[h][p0][0];
#pragma unroll
    for (int ky = 0; ky < 5; ++ky) {
#pragma unroll
      for (int kx = 0; kx < 5; ++kx) {
        const int tap = ky * 5 + kx;
        const float4 w4 =
            *reinterpret_cast<const float4*>(&wbase[tap * 64 + grp * 8]);
        const float w4b = wbase[tap * 64 + grp * 8 + 4];
#pragma unroll
        for (int pooled = 0; pooled < 2; ++pooled) {
#pragma unroll
          for (int dy = 0; dy < 2; ++dy) {
#pragma unroll
            for (int dx = 0; dx < 2; ++dx) {
              const int u = pooled * 4 + dy * 2 + dx;
              const float iv = p[ky + dy][pooled * 2 + dx + kx];
              acc[0][u] += iv * w4.x;
              acc[1][u] += iv * w4.y;
              acc[2][u] += iv * w4.z;
              acc[3][u] += iv * w4.w;
              acc[4][u] += iv * w4b;
            }
          }
        }
      }
    }
    if (s < 9) {  // late LDS writes into other parity
#pragma unroll
      for (int k = 0; k < 4; ++k) {
        const int e = tid + k * 256;
        if (e < 800) {
          const int str = e / 400;
          const int i4 = e - str * 400;
          wlf4[(str * 2 + ((s + 1) & 1)) * 400 + i4] = sv[k];
        }
      }
    }
    __syncthreads();
  }

  // ---- merge ic-halves, pool, relu, write feats (f32 + bf16 hi/lo) ----
  const int midx = (grp << 3) | pp;
  if (h == 1) {
#pragma unroll
    for (int q = 0; q < 5; ++q)
#pragma unroll
      for (int u = 0; u < 8; ++u) mg[slot][midx][q * 8 + u] = acc[q][u];
  }
  __syncthreads();
  if (h == 0) {
    const int pos0 = (pp >> 1) * 4 + (pp & 1) * 2;
#pragma unroll
    for (int q = 0; q < 5; ++q) {
      const int ch = grp * 5 + q;
      float a[8];
#pragma unroll
      for (int u = 0; u < 8; ++u) a[u] = acc[q][u] + mg[slot][midx][q * 8 + u];
      const float bb = bl2[ch];
      const float r0v =
          fmaxf(fmaxf(fmaxf(a[0], a[1]), fmaxf(a[2], a[3])) + bb, 0.f);
      const float r1v =
          fmaxf(fmaxf(fmaxf(a[4], a[5]), fmaxf(a[6], a[7])) + bb, 0.f);
      const int off = imgId * 640 + ch * 16 + pos0;
      *reinterpret_cast<float2*>(&feats[off]) = make_float2(r0v, r1v);
      const unsigned short h0 = f2bf(r0v), h1v = f2bf(r1v);
      ushort2 hv; hv.x = h0; hv.y = h1v;
      ushort2 lv;
      lv.x = f2bf(r0v - bf2f(h0));
      lv.y = f2bf(r1v - bf2f(h1v));
      *reinterpret_cast<ushort2*>(&fh[off]) = hv;
      *reinterpret_cast<ushort2*>(&fl[off]) = lv;
    }
  }
}

// ---- k3m: M = feats @ T^T via bf16x3 MFMA ---------------------------------
// grid (16 j-tiles, 8 i-tiles), 256 thr = 4 waves. Tile 64x64, wave = 16 rows.
__global__ __launch_bounds__(256) void k3m_gemm(
    const unsigned short* __restrict__ fh, const unsigned short* __restrict__ fl,
    const unsigned short* __restrict__ Th, const unsigned short* __restrict__ Tl,
    float* __restrict__ M) {
  __shared__ short Ah[64][40];
  __shared__ short Al[64][40];
  __shared__ short Bh[64][40];
  __shared__ short Bl[64][40];
  const int tid = threadIdx.x;
  const int i0 = blockIdx.y * 64;
  const int j0 = blockIdx.x * 64;
  const int row = tid >> 2, kq = tid & 3;
  const int l = tid & 63, w = tid >> 6;
  const int fr = l & 15, kslot = (l >> 4) * 8;

  f32x4 acc[4];
#pragma unroll
  for (int js = 0; js < 4; ++js) acc[js] = (f32x4){0.f, 0.f, 0.f, 0.f};

  for (int k0 = 0; k0 < 640; k0 += 32) {
    const int ga = (i0 + row) * 640 + k0 + kq * 8;
    const int gb = (j0 + row) * 640 + k0 + kq * 8;
    const uint4 vah = *reinterpret_cast<const uint4*>(fh + ga);
    const uint4 val_ = *reinterpret_cast<const uint4*>(fl + ga);
    const uint4 vbh = *reinterpret_cast<const uint4*>(Th + gb);
    const uint4 vbl = *reinterpret_cast<const uint4*>(Tl + gb);
    __syncthreads();  // prior step's readers done before overwrite
    *reinterpret_cast<uint4*>(&Ah[row][kq * 8]) = vah;
    *reinterpret_cast<uint4*>(&Al[row][kq * 8]) = val_;
    *reinterpret_cast<uint4*>(&Bh[row][kq * 8]) = vbh;
    *reinterpret_cast<uint4*>(&Bl[row][kq * 8]) = vbl;
    __syncthreads();
    const bf16x8 aH = *reinterpret_cast<const bf16x8*>(&Ah[w * 16 + fr][kslot]);
    const bf16x8 aL = *reinterpret_cast<const bf16x8*>(&Al[w * 16 + fr][kslot]);
#pragma unroll
    for (int js = 0; js < 4; ++js) {
      const bf16x8 bH =
          *reinterpret_cast<const bf16x8*>(&Bh[js * 16 + fr][kslot]);
      const bf16x8 bL =
          *reinterpret_cast<const bf16x8*>(&Bl[js * 16 + fr][kslot]);
      acc[js] = __builtin_amdgcn_mfma_f32_16x16x32_bf16(aH, bH, acc[js], 0, 0, 0);
      acc[js] = __builtin_amdgcn_mfma_f32_16x16x32_bf16(aL, bH, acc[js], 0, 0, 0);
      acc[js] = __builtin_amdgcn_mfma_f32_16x16x32_bf16(aH, bL, acc[js], 0, 0, 0);
    }
  }
  // C/D layout: col = lane&15, row = (lane>>4)*4 + reg  [m89-verified]
#pragma unroll
  for (int js = 0; js < 4; ++js) {
#pragma unroll
    for (int r = 0; r < 4; ++r) {
      M[(i0 + w * 16 + (l >> 4) * 4 + r) * 1024 + j0 + js * 16 + (l & 15)] =
          acc[js][r];
    }
  }
}

// ---- k4: partial closeness, LDS-staged swizzled j-rows --------------------
__global__ __launch_bounds__(256) void k4_mbd(const float* __restrict__ M,
                                              float* __restrict__ cp) {
  __shared__ float4 jb4[2][4][256];
  const int bid = blockIdx.x;
  const int ig = bid >> 4;
  const int jq = bid & 15;
  const int t = threadIdx.x;
  const int b = t & 63;
  const int g = t >> 6;
  const int i0 = ig * 16 + g * 4;
  const float4* Mf4 = reinterpret_cast<const float4*>(M);

  float4 mi[4][4];
#pragma unroll
  for (int u = 0; u < 4; ++u) {
#pragma unroll
    for (int q = 0; q < 4; ++q) mi[u][q] = Mf4[(i0 + u) * 256 + b * 4 + q];
  }
  const int wslot = (t >> 2) * 4 + ((t & 3) ^ ((t >> 3) & 3));
  {
#pragma unroll
    for (int k = 0; k < 4; ++k)
      jb4[0][k][wslot] = Mf4[(jq * 32 + k) * 256 + t];
  }
  __syncthreads();

  float acc[4] = {0.f, 0.f, 0.f, 0.f};
  const int xr = (b >> 1) & 3;
  for (int c = 0; c < 8; ++c) {
    float4 st[4];
    if (c < 7) {
#pragma unroll
      for (int k = 0; k < 4; ++k)
        st[k] = Mf4[(jq * 32 + (c + 1) * 4 + k) * 256 + t];
    }
    const int cbuf = c & 1;
#pragma unroll
    for (int jj = 0; jj < 4; ++jj) {
      const float4* rowp = jb4[cbuf][jj];
      float4 mj[4];
#pragma unroll
      for (int q = 0; q < 4; ++q) mj[q] = rowp[b * 4 + (q ^ xr)];
#pragma unroll
      for (int u = 0; u < 4; ++u) {
        float dist =
            fabsf(mi[u][0].x - mj[0].x) + fabsf(mi[u][0].y - mj[0].y) +
            fabsf(mi[u][0].z - mj[0].z) + fabsf(mi[u][0].w - mj[0].w) +
            fabsf(mi[u][1].x - mj[1].x) + fabsf(mi[u][1].y - mj[1].y) +
            fabsf(mi[u][1].z - mj[1].z) + fabsf(mi[u][1].w - mj[1].w) +
            fabsf(mi[u][2].x - mj[2].x) + fabsf(mi[u][2].y - mj[2].y) +
            fabsf(mi[u][2].z - mj[2].z) + fabsf(mi[u][2].w - mj[2].w) +
            fabsf(mi[u][3].x - mj[3].x) + fabsf(mi[u][3].y - mj[3].y) +
            fabsf(mi[u][3].z - mj[3].z) + fabsf(mi[u][3].w - mj[3].w);
        acc[u] += __expf(-dist);
      }
    }
    if (c < 7) {
#pragma unroll
      for (int k = 0; k < 4; ++k) jb4[(c + 1) & 1][k][wslot] = st[k];
    }
    __syncthreads();
  }
#pragma unroll
  for (int u = 0; u < 4; ++u)
    cp[(jq * 512 + i0 + u) * 64 + b] = acc[u];
}

// ---- k5: head -------------------------------------------------------------
__global__ __launch_bounds__(256) void k5_head(
    const float* __restrict__ feats, const float* __restrict__ cp,
    const float* __restrict__ w1, const float* __restrict__ b1,
    const float* __restrict__ w2, const float* __restrict__ b2,
    float* __restrict__ out) {
  __shared__ __align__(16) float v[704];
  __shared__ float hb[100];
  const int i = blockIdx.x;
  const int tid = threadIdx.x;
  float4* v4 = reinterpret_cast<float4*>(v);
  if (tid < 160)
    v4[tid] = reinterpret_cast<const float4*>(feats + i * 640)[tid];
  if (tid >= 192) {
    const int bb = tid - 192;
    float s = 0.f;
#pragma unroll
    for (int q = 0; q < 16; ++q) s += cp[(q * 512 + i) * 64 + bb];
    v[640 + bb] = s;
  }
  __syncthreads();
  const int wave = tid >> 6;
  const int lane = tid & 63;
  for (int r = wave; r < 100; r += 4) {
    const float4* wr = reinterpret_cast<const float4*>(w1 + r * 704);
    const float4 wa = wr[lane];
    const float4 wb = wr[lane + 64];
    const float4 va = v4[lane];
    const float4 vb = v4[lane + 64];
    float s = wa.x * va.x + wa.y * va.y + wa.z * va.z + wa.w * va.w +
              wb.x * vb.x + wb.y * vb.y + wb.z * vb.z + wb.w * vb.w;
    if (lane < 48) {
      const float4 wc = wr[lane + 128];
      const float4 vc = v4[lane + 128];
      s += wc.x * vc.x + wc.y * vc.y + wc.z * vc.z + wc.w * vc.w;
    }
#pragma unroll
    for (int off = 32; off; off >>= 1) s += __shfl_xor(s, off);
    if (lane == 0) hb[r] = fmaxf(s + b1[r], 0.f) * w2[r];
  }
  __syncthreads();
  if (tid < 64) {
    float s = hb[tid] + ((tid < 36) ? hb[tid + 64] : 0.f);
#pragma unroll
    for (int off = 32; off; off >>= 1) s += __shfl_xor(s, off);
    if (tid == 0) out[i] = 1.f / (1.f + __expf(-(s + b2[0])));
  }
}

extern "C" void kernel_launch(void* const* d_in, const int* in_sizes, int n_in,
                              void* d_out, int out_size, void* d_ws,
                              size_t ws_size, hipStream_t stream) {
  const float* x   = (const float*)d_in[0];
  const float* c1w = (const float*)d_in[1];
  const float* c1b = (const float*)d_in[2];
  const float* c2w = (const float*)d_in[3];
  const float* c2b = (const float*)d_in[4];
  const float* T   = (const float*)d_in[5];
  const float* f1w = (const float*)d_in[6];
  const float* f1b = (const float*)d_in[7];
  const float* f2w = (const float*)d_in[8];
  const float* f2b = (const float*)d_in[9];
  float* out = (float*)d_out;

  float* feats = (float*)d_ws;                    // 327680 f
  float* M     = feats + 327680;                  // 524288 f
  float* cp    = M + 524288;                      // 524288 f
  float* ws2   = cp + 524288;                     // 32000 f
  unsigned short* fh = (unsigned short*)(ws2 + 32000);  // 327680 u16
  unsigned short* fl = fh + 327680;
  unsigned short* Th = fl + 327680;               // 655360 u16
  unsigned short* Tl = Th + 655360;
  // total ~9.6 MB

  kP_prep<<<2560, 256, 0, stream>>>(c2w, T, ws2, Th, Tl);
  kC_conv<<<256, 256, 0, stream>>>(x, c1w, c1b, ws2, c2b, feats, fh, fl);
  k3m_gemm<<<dim3(16, 8), 256, 0, stream>>>(fh, fl, Th, Tl, M);
  k4_mbd<<<512, 256, 0, stream>>>(M, cp);
  k5_head<<<512, 256, 0, stream>>>(feats, cp, f1w, f1b, f2w, f2b, out);
}